// Round 7
// baseline (780.459 us; speedup 1.0000x reference)
//
#include <hip/hip_runtime.h>
#include <cstdint>

typedef unsigned short u16;
using bf16x8 = __attribute__((ext_vector_type(8))) __bf16;
using f32x4  = __attribute__((ext_vector_type(4))) float;

#define T_TOK 16384   // B * N_OBJ
#define E_NUM 8

__device__ __forceinline__ u16 f2bf(float f) {
    union { float f; unsigned u; } v; v.f = f;
    unsigned r = (v.u + 0x7FFFu + ((v.u >> 16) & 1u)) >> 16;
    return (u16)r;
}

// ---------------- prep: W (E,1024,1024) f32 -> WT (E,1024,1024) bf16 transposed ----------------
__global__ __launch_bounds__(256) void k_transpose(const float* __restrict__ W, u16* __restrict__ WT) {
    __shared__ float tile[32][33];
    int e = blockIdx.z;
    int d0 = blockIdx.x << 5, h0 = blockIdx.y << 5;
    int tx = threadIdx.x & 31, ty = threadIdx.x >> 5;   // 32x8
    const size_t eo = (size_t)e << 20;
#pragma unroll
    for (int i = 0; i < 4; ++i) {
        int r = ty + i * 8;
        tile[r][tx] = W[eo + (size_t)(d0 + r) * 1024 + h0 + tx];
    }
    __syncthreads();
#pragma unroll
    for (int i = 0; i < 4; ++i) {
        int r = ty + i * 8;
        WT[eo + (size_t)(h0 + r) * 1024 + d0 + tx] = f2bf(tile[tx][r]);
    }
}

// ---------------- router: exact fp32 logits, top-2; writes per-token info; folds x->bf16 ----------------
__global__ __launch_bounds__(256) void k_router(const float* __restrict__ x, const float* __restrict__ Wr,
                                                const float* __restrict__ br,
                                                int* __restrict__ tinfo, float* __restrict__ c1arr,
                                                u16* __restrict__ xbf) {
    const int wave = threadIdx.x >> 6, lane = threadIdx.x & 63;
    const int t = (blockIdx.x << 2) + wave;
    const float* xr = x + (size_t)t * 1024;
    u16* xbr = xbf + (size_t)t * 1024;
    float acc[8] = {0, 0, 0, 0, 0, 0, 0, 0};
#pragma unroll
    for (int i = 0; i < 16; ++i) {
        int d = (i << 6) + lane;
        float xv = xr[d];
        xbr[d] = f2bf(xv);
        float4 w0 = *(const float4*)(Wr + d * 8);
        float4 w1 = *(const float4*)(Wr + d * 8 + 4);
        acc[0] += xv * w0.x; acc[1] += xv * w0.y; acc[2] += xv * w0.z; acc[3] += xv * w0.w;
        acc[4] += xv * w1.x; acc[5] += xv * w1.y; acc[6] += xv * w1.z; acc[7] += xv * w1.w;
    }
#pragma unroll
    for (int off = 32; off > 0; off >>= 1)
#pragma unroll
        for (int e = 0; e < 8; ++e) acc[e] += __shfl_xor(acc[e], off);

    if (lane == 0) {
        float v1 = -1e30f, v2 = -1e30f; int i1 = 0, i2 = 0;
#pragma unroll
        for (int e = 0; e < 8; ++e) {
            float v = acc[e] + br[e];
            if (v > v1) { v2 = v1; i2 = i1; v1 = v; i1 = e; }
            else if (v > v2) { v2 = v; i2 = e; }
        }
        float c1 = 1.f / (1.f + expf(v2 - v1));
        tinfo[t] = i1 | (i2 << 4);
        c1arr[t] = c1;
    }
}

// ---------------- scatter: LDS histogram -> per-block base -> 8 per-expert lists ----------------
__global__ __launch_bounds__(1024) void k_scatter(const int* __restrict__ tinfo, const float* __restrict__ c1arr,
                                                  int* __restrict__ cnt, int* __restrict__ tok,
                                                  float* __restrict__ coef) {
    __shared__ int lcnt[8];
    __shared__ int lbase[8];
    const int tid = threadIdx.x;
    const int t = blockIdx.x * 1024 + tid;
    if (tid < 8) lcnt[tid] = 0;
    __syncthreads();
    int info = tinfo[t];
    float c1 = c1arr[t];
    int g1 = info & 15;
    int g2 = (info >> 4) & 15;
    int o1 = atomicAdd(&lcnt[g1], 1);
    int o2 = atomicAdd(&lcnt[g2], 1);
    __syncthreads();
    if (tid < 8) lbase[tid] = atomicAdd(cnt + tid, lcnt[tid]);
    __syncthreads();
    int p1 = lbase[g1] + o1;
    tok[(g1 << 14) + p1] = t; coef[(g1 << 14) + p1] = c1;
    int p2 = lbase[g2] + o2;
    tok[(g2 << 14) + p2] = t; coef[(g2 << 14) + p2] = 1.f - c1;
}

// ---------------- grouped GEMM: BARRIER-FREE, LDS-FREE register-direct K-loop ----------------
// AITER-style MFMA<->global_load interleave, expressible in plain HIP because the
// 16x16x32 A/B fragment is directly loadable: lane l needs row (l&15), bytes
// (l>>4)*16 + kc*64 of that row -- one global_load_dwordx4 whose K-offset (kc*64 <=
// 1984B) fits the 13-bit immediate. So the K-loop is 12 loads + 32 MFMA per step,
// ZERO address VALU, ZERO LDS, ZERO barriers; the compiler's auto-waitcnt produces
// counted vmcnt waits and is free to pipeline across steps (pure dataflow).
// Per-wave output 128x64 (acc[8][4]); block = 4 waves sharing ONE A row-tile
// (gathered A rows hit L1 for 3 of 4 waves) x 4 col-blocks = 128x256 block tile.
// Waves never synchronize -- no convoy, no barrier drain.
// PHASE 0: h = relu(gather(xbf) @ W1T + b1) -> hbuf (bf16)
// PHASE 1: out[tok] += coef * (hbuf @ W2T + b2)   (atomicAdd, out pre-zeroed)
template <int PHASE>
__global__ __launch_bounds__(256, 2) void k_gemm(
    const int* __restrict__ cnt, const int* __restrict__ tok, const float* __restrict__ coef,
    const u16* __restrict__ xbf, const u16* __restrict__ w1t, const u16* __restrict__ w2t,
    const float* __restrict__ b1, const float* __restrict__ b2,
    u16* __restrict__ hbuf, float* __restrict__ out)
{
    const int tid = threadIdx.x;

    // XCD-aware remap (bijective: 1056 = 8*132): each XCD owns 132 consecutive lin;
    // consecutive lin = same A row-tile sweeping col-quads -> A L1/L2 reuse, B panel
    // (2MB/expert) stays L2-resident per XCD.
    int bid = blockIdx.x + blockIdx.y * 132;            // hw flat id, 1056 total
    int lin = (bid & 7) * 132 + (bid >> 3);
    int xt = lin >> 2, yc = lin & 3;                    // row-tile (128 rows), col-quad (256 cols)

    // uniform scan over global cnt[]: which (group, row-tile)?
    int g = -1, tile = 0, r0 = 0, mt = xt, rb = 0, cg = 0;
#pragma unroll
    for (int gg = 0; gg < 8; ++gg) {
        int c = cnt[gg], tg = (c + 127) >> 7;
        if (g < 0) {
            if (mt < tg) { g = gg; tile = mt; r0 = rb + (mt << 7); cg = c; }
            else mt -= tg;
        }
        rb += c;
    }
    if (g < 0) return;
    const int e = g;
    const int rowlim = cg - (tile << 7);
    const int gbase = (g << 14) + (tile << 7);

    const int w = tid >> 6, l = tid & 63;
    const int l15 = l & 15;
    const int lk = (l >> 4) << 3;                       // lane k-offset, elements
    const u16* asrc = (PHASE == 0) ? xbf : hbuf;
    const u16* bsrc = (PHASE == 0) ? w1t : w2t;
    const int colq = (yc << 8) + (w << 6);              // this wave's 64-col block

    // per-lane fragment base pointers: 8 A rows-groups, 4 B col-groups. Constant
    // through the whole K-loop; every load uses a literal offset kc*64.
    const u16* aptr[8];
#pragma unroll
    for (int m = 0; m < 8; ++m) {
        int row = (m << 4) + l15;
        int arow;
        if (PHASE == 0) arow = (row < rowlim) ? tok[gbase + row] : 0;
        else            arow = r0 + row;
        aptr[m] = asrc + ((size_t)arow << 10) + lk;
    }
    const u16* bptr[4];
#pragma unroll
    for (int n = 0; n < 4; ++n) {
        int col = colq + (n << 4) + l15;
        bptr[n] = bsrc + (((size_t)(e << 10) + col) << 10) + lk;
    }

    f32x4 acc[8][4];
#pragma unroll
    for (int mi = 0; mi < 8; ++mi)
#pragma unroll
        for (int ni = 0; ni < 4; ++ni) { acc[mi][ni][0] = 0.f; acc[mi][ni][1] = 0.f; acc[mi][ni][2] = 0.f; acc[mi][ni][3] = 0.f; }

    // K-loop: 32 steps of k=32. Fully unrolled; all frag indices static (no scratch).
#pragma unroll
    for (int kc = 0; kc < 32; ++kc) {
        const int kb = kc << 5;                         // element offset = 64B * kc
        bf16x8 bfr[4], af[8];
#pragma unroll
        for (int n = 0; n < 4; ++n) bfr[n] = *(const bf16x8*)(bptr[n] + kb);
#pragma unroll
        for (int m = 0; m < 8; ++m) af[m] = *(const bf16x8*)(aptr[m] + kb);
#pragma unroll
        for (int m = 0; m < 8; ++m)
#pragma unroll
            for (int n = 0; n < 4; ++n)
                acc[m][n] = __builtin_amdgcn_mfma_f32_16x16x32_bf16(af[m], bfr[n], acc[m][n], 0, 0, 0);
    }

    const int rq = (l >> 4) << 2;
#pragma unroll
    for (int ni = 0; ni < 4; ++ni) {
        int ccol = colq + (ni << 4) + l15;
        float bias = (PHASE == 0 ? b1 : b2)[((size_t)e << 10) + ccol];
#pragma unroll
        for (int mi = 0; mi < 8; ++mi) {
            int rbase = (mi << 4) + rq;
#pragma unroll
            for (int j = 0; j < 4; ++j) {
                int r = rbase + j;
                if (r < rowlim) {
                    float v = acc[mi][ni][j] + bias;
                    if constexpr (PHASE == 0) {
                        v = fmaxf(v, 0.f);
                        hbuf[(size_t)(r0 + r) * 1024 + ccol] = f2bf(v);
                    } else {
                        int gi = gbase + r;
                        atomicAdd(out + ((size_t)tok[gi] << 10) + ccol, v * coef[gi]);
                    }
                }
            }
        }
    }
}

// ---------------- insurance fallback (ws too small): slow but correct ----------------
__global__ __launch_bounds__(256) void k_naive(const float* __restrict__ x, const float* __restrict__ Wr,
    const float* __restrict__ br, const float* __restrict__ W1, const float* __restrict__ b1,
    const float* __restrict__ W2, const float* __restrict__ b2, float* __restrict__ out)
{
    __shared__ float xs[1024];
    __shared__ float hs[1024];
    __shared__ float red[4];
    __shared__ float lg[8];
    const int tid = threadIdx.x;
    const size_t t = blockIdx.x;
    for (int i = tid; i < 1024; i += 256) xs[i] = x[t * 1024 + i];
    __syncthreads();
    float lacc[8] = {0, 0, 0, 0, 0, 0, 0, 0};
    for (int d = tid; d < 1024; d += 256) {
        float xv = xs[d];
#pragma unroll
        for (int e = 0; e < 8; ++e) lacc[e] += xv * Wr[d * 8 + e];
    }
    for (int e = 0; e < 8; ++e) {
        float v = lacc[e];
        for (int off = 32; off > 0; off >>= 1) v += __shfl_xor(v, off);
        if ((tid & 63) == 0) red[tid >> 6] = v;
        __syncthreads();
        if (tid == 0) lg[e] = red[0] + red[1] + red[2] + red[3] + br[e];
        __syncthreads();
    }
    float v1 = -1e30f, v2 = -1e30f; int i1 = 0, i2 = 0;
    for (int e = 0; e < 8; ++e) {
        float v = lg[e];
        if (v > v1) { v2 = v1; i2 = i1; v1 = v; i1 = e; }
        else if (v > v2) { v2 = v; i2 = e; }
    }
    float c1 = 1.f / (1.f + expf(v2 - v1)), c2 = 1.f - c1;
    float yacc[4] = {0, 0, 0, 0};
    for (int slot = 0; slot < 2; ++slot) {
        int e = slot ? i2 : i1;
        float cw = slot ? c2 : c1;
        __syncthreads();
        float ha[4];
        for (int jb = 0; jb < 4; ++jb) {
            int j = (jb << 8) + tid;
            float a = b1[(e << 10) + j];
            for (int d = 0; d < 1024; ++d) a += xs[d] * W1[(((size_t)e << 10) + d) * 1024 + j];
            ha[jb] = fmaxf(a, 0.f);
        }
        for (int jb = 0; jb < 4; ++jb) hs[(jb << 8) + tid] = ha[jb];
        __syncthreads();
        for (int ob = 0; ob < 4; ++ob) {
            int o = (ob << 8) + tid;
            float a = b2[(e << 10) + o];
            for (int h = 0; h < 1024; ++h) a += hs[h] * W2[(((size_t)e << 10) + h) * 1024 + o];
            yacc[ob] += cw * a;
        }
    }
    for (int ob = 0; ob < 4; ++ob) out[t * 1024 + (ob << 8) + tid] = yacc[ob];
}

extern "C" void kernel_launch(void* const* d_in, const int* in_sizes, int n_in,
                              void* d_out, int out_size, void* d_ws, size_t ws_size,
                              hipStream_t stream) {
    const float* x  = (const float*)d_in[0];
    const float* Wr = (const float*)d_in[1];
    const float* br = (const float*)d_in[2];
    const float* W1 = (const float*)d_in[3];
    const float* b1 = (const float*)d_in[4];
    const float* W2 = (const float*)d_in[5];
    const float* b2 = (const float*)d_in[6];
    float* out = (float*)d_out;

    const size_t OFF_TOK   = (size_t)1 << 20;
    const size_t OFF_COEF  = (size_t)2 << 20;
    const size_t OFF_TINFO = (size_t)3 << 20;
    const size_t OFF_C1    = OFF_TINFO + (size_t)T_TOK * 4;
    const size_t OFF_XBF   = (size_t)4 << 20;
    const size_t OFF_W1T   = OFF_XBF + (size_t)T_TOK * 1024 * 2;          // +32MB
    const size_t OFF_W2T   = OFF_W1T + (size_t)E_NUM * 1024 * 1024 * 2;   // +16MB
    const size_t OFF_H     = OFF_W2T + (size_t)E_NUM * 1024 * 1024 * 2;   // +16MB
    const size_t WS_NEED   = OFF_H + (size_t)(2 * T_TOK + 512) * 1024 * 2; // h + ragged pad

    if (ws_size < WS_NEED) {
        k_naive<<<T_TOK, 256, 0, stream>>>(x, Wr, br, W1, b1, W2, b2, out);
        return;
    }

    char* ws = (char*)d_ws;
    int*   cnt   = (int*)ws;
    int*   tok   = (int*)(ws + OFF_TOK);
    float* coef  = (float*)(ws + OFF_COEF);
    int*   tinfo = (int*)(ws + OFF_TINFO);
    float* c1arr = (float*)(ws + OFF_C1);
    u16*   xbf   = (u16*)(ws + OFF_XBF);
    u16*   w1t   = (u16*)(ws + OFF_W1T);
    u16*   w2t   = (u16*)(ws + OFF_W2T);
    u16*   hbuf  = (u16*)(ws + OFF_H);

    hipMemsetAsync(cnt, 0, 64, stream);
    hipMemsetAsync(d_out, 0, (size_t)out_size * sizeof(float), stream);
    k_transpose<<<dim3(32, 32, 8), 256, 0, stream>>>(W1, w1t);
    k_transpose<<<dim3(32, 32, 8), 256, 0, stream>>>(W2, w2t);
    k_router<<<4096, 256, 0, stream>>>(x, Wr, br, tinfo, c1arr, xbf);
    k_scatter<<<16, 1024, 0, stream>>>(tinfo, c1arr, cnt, tok, coef);
    dim3 gg(132, 8);
    k_gemm<0><<<gg, 256, 0, stream>>>(cnt, tok, coef, xbf, w1t, w2t, b1, b2, hbuf, out);
    k_gemm<1><<<gg, 256, 0, stream>>>(cnt, tok, coef, xbf, w1t, w2t, b1, b2, hbuf, out);
}

// Round 8
// 488.279 us; speedup vs baseline: 1.5984x; 1.5984x over previous
//
#include <hip/hip_runtime.h>
#include <cstdint>

typedef unsigned short u16;
using bf16x8 = __attribute__((ext_vector_type(8))) __bf16;
using f32x4  = __attribute__((ext_vector_type(4))) float;

#define T_TOK 16384   // B * N_OBJ
#define E_NUM 8

__device__ __forceinline__ u16 f2bf(float f) {
    union { float f; unsigned u; } v; v.f = f;
    unsigned r = (v.u + 0x7FFFu + ((v.u >> 16) & 1u)) >> 16;
    return (u16)r;
}

__device__ __forceinline__ void gload_lds16(const void* g, void* l) {
    __builtin_amdgcn_global_load_lds(
        (const __attribute__((address_space(1))) void*)g,
        (__attribute__((address_space(3))) void*)l, 16, 0, 0);
}

// ---------------- prep: W (E,1024,1024) f32 -> WT (E,1024,1024) bf16 transposed ----------------
__global__ __launch_bounds__(256) void k_transpose(const float* __restrict__ W, u16* __restrict__ WT) {
    __shared__ float tile[32][33];
    int e = blockIdx.z;
    int d0 = blockIdx.x << 5, h0 = blockIdx.y << 5;
    int tx = threadIdx.x & 31, ty = threadIdx.x >> 5;   // 32x8
    const size_t eo = (size_t)e << 20;
#pragma unroll
    for (int i = 0; i < 4; ++i) {
        int r = ty + i * 8;
        tile[r][tx] = W[eo + (size_t)(d0 + r) * 1024 + h0 + tx];
    }
    __syncthreads();
#pragma unroll
    for (int i = 0; i < 4; ++i) {
        int r = ty + i * 8;
        WT[eo + (size_t)(h0 + r) * 1024 + d0 + tx] = f2bf(tile[tx][r]);
    }
}

// ---------------- router: exact fp32 logits, top-2; writes per-token info; folds x->bf16 ----------------
__global__ __launch_bounds__(256) void k_router(const float* __restrict__ x, const float* __restrict__ Wr,
                                                const float* __restrict__ br,
                                                int* __restrict__ tinfo, float* __restrict__ c1arr,
                                                u16* __restrict__ xbf) {
    const int wave = threadIdx.x >> 6, lane = threadIdx.x & 63;
    const int t = (blockIdx.x << 2) + wave;
    const float* xr = x + (size_t)t * 1024;
    u16* xbr = xbf + (size_t)t * 1024;
    float acc[8] = {0, 0, 0, 0, 0, 0, 0, 0};
#pragma unroll
    for (int i = 0; i < 16; ++i) {
        int d = (i << 6) + lane;
        float xv = xr[d];
        xbr[d] = f2bf(xv);
        float4 w0 = *(const float4*)(Wr + d * 8);
        float4 w1 = *(const float4*)(Wr + d * 8 + 4);
        acc[0] += xv * w0.x; acc[1] += xv * w0.y; acc[2] += xv * w0.z; acc[3] += xv * w0.w;
        acc[4] += xv * w1.x; acc[5] += xv * w1.y; acc[6] += xv * w1.z; acc[7] += xv * w1.w;
    }
#pragma unroll
    for (int off = 32; off > 0; off >>= 1)
#pragma unroll
        for (int e = 0; e < 8; ++e) acc[e] += __shfl_xor(acc[e], off);

    if (lane == 0) {
        float v1 = -1e30f, v2 = -1e30f; int i1 = 0, i2 = 0;
#pragma unroll
        for (int e = 0; e < 8; ++e) {
            float v = acc[e] + br[e];
            if (v > v1) { v2 = v1; i2 = i1; v1 = v; i1 = e; }
            else if (v > v2) { v2 = v; i2 = e; }
        }
        float c1 = 1.f / (1.f + expf(v2 - v1));
        tinfo[t] = i1 | (i2 << 4);
        c1arr[t] = c1;
    }
}

// ---------------- scatter: LDS histogram -> per-block base -> 8 per-expert lists ----------------
__global__ __launch_bounds__(1024) void k_scatter(const int* __restrict__ tinfo, const float* __restrict__ c1arr,
                                                  int* __restrict__ cnt, int* __restrict__ tok,
                                                  float* __restrict__ coef) {
    __shared__ int lcnt[8];
    __shared__ int lbase[8];
    const int tid = threadIdx.x;
    const int t = blockIdx.x * 1024 + tid;
    if (tid < 8) lcnt[tid] = 0;
    __syncthreads();
    int info = tinfo[t];
    float c1 = c1arr[t];
    int g1 = info & 15;
    int g2 = (info >> 4) & 15;
    int o1 = atomicAdd(&lcnt[g1], 1);
    int o2 = atomicAdd(&lcnt[g2], 1);
    __syncthreads();
    if (tid < 8) lbase[tid] = atomicAdd(cnt + tid, lcnt[tid]);
    __syncthreads();
    int p1 = lbase[g1] + o1;
    tok[(g1 << 14) + p1] = t; coef[(g1 << 14) + p1] = c1;
    int p2 = lbase[g2] + o2;
    tok[(g2 << 14) + p2] = t; coef[(g2 << 14) + p2] = 1.f - c1;
}

// ---------------- grouped GEMM, 256x256, BK=64, STATIC dbuf, minimal 2-phase (m248 anchor) ----------------
// Why 256^2: the binding resource (diagnosed R6/R7) is per-CU staging ingress --
// with 64-wide N tiles every A row rides the L3->CU path 16x. At 256^2, A is
// restaged only 4x and total staged traffic drops 1.6GB -> 0.5GB/phase.
// Why static buffers a0/a1/b0/b1 + unroll x2: R2 (same geometry, dynamic cur^1
// indexing) was serialized by alias-forced waits (R3 diagnosis). Every buffer
// reference here is a distinct static object.
// Schedule per tile (T3 minimal 2-phase): STAGE(next tile into other buf, stays in
// flight) -> COMPUTE(current: 24 ds_read_b128 + 64 MFMA/wave) -> ONE __syncthreads
// (vmcnt0+lgkm0+barrier: staged loads landed, all waves done reading current).
// 8 waves (2Mx4N), per-wave 128x64 = acc[8][4]. 128KB LDS -> 1 block/CU.
// Col-tiles of a row-tile are launch-adjacent on the same XCD -> A re-reads L2-hit.
// PHASE 0: h = relu(gather(xbf) @ W1T + b1) -> hbuf (bf16)
// PHASE 1: out[tok] += coef * (hbuf @ W2T + b2)   (atomicAdd, out pre-zeroed)
template <int PHASE>
__global__ __launch_bounds__(512, 2) void k_gemm(
    const int* __restrict__ cnt, const int* __restrict__ tok, const float* __restrict__ coef,
    const u16* __restrict__ xbf, const u16* __restrict__ w1t, const u16* __restrict__ w2t,
    const float* __restrict__ b1, const float* __restrict__ b2,
    u16* __restrict__ hbuf, float* __restrict__ out)
{
    __shared__ u16 a0_s[256 * 64];   // 32 KB
    __shared__ u16 a1_s[256 * 64];   // 32 KB
    __shared__ u16 b0_s[256 * 64];   // 32 KB
    __shared__ u16 b1_s[256 * 64];   // 32 KB  -> 128 KB total
    const int tid = threadIdx.x;

    // XCD-aware remap (bijective: 576 = 8*72); consecutive lin within an XCD share
    // a row-tile (xt) sweeping its 4 col-tiles -> gathered A rows are L2-hot for
    // the 2nd-4th col-tile blocks.
    int bid = blockIdx.x + blockIdx.y * 72;             // hw flat id, 576 total
    int lin = (bid & 7) * 72 + (bid >> 3);
    int xt = lin >> 2, yt = lin & 3;

    // uniform scan over global cnt[]: which (group, row-tile)?
    int g = -1, tile = 0, r0 = 0, mt = xt, rb = 0, cg = 0;
#pragma unroll
    for (int gg = 0; gg < 8; ++gg) {
        int c = cnt[gg], tg = (c + 255) >> 8;
        if (g < 0) {
            if (mt < tg) { g = gg; tile = mt; r0 = rb + (mt << 8); cg = c; }
            else mt -= tg;
        }
        rb += c;
    }
    if (g < 0) return;
    const int e = g;
    const int nb = yt << 8;
    const int rowlim = cg - (tile << 8);
    const int gbase = (g << 14) + (tile << 8);

    const int w = tid >> 6, l = tid & 63;       // 8 waves
    const int wm = w >> 2, wn = w & 3;          // 2M x 4N
    const int l15 = l & 15;
    const u16* asrc = (PHASE == 0) ? xbf : hbuf;
    const u16* bsrc = (PHASE == 0) ? w1t : w2t;
    const size_t brow0 = ((size_t)e << 10) + nb;

    // T2 swizzle: LDS linear for gload_lds; global SOURCE col pre-XORed; reads XOR back.
    const int sw = ((l & 7) ^ (l >> 3)) << 3;   // staging source col offset (elements)
    const int xk = (l & 7) << 3;                // read col XOR key (frag row&7 == l&7)

    // staging: A/B each 4 slots x 64 rows; per-thread row = j*64 + (tid>>3)
    const u16* aptr[4]; const u16* bptr[4]; int ldso[4];
#pragma unroll
    for (int j = 0; j < 4; ++j) {
        int row = (j << 6) + (tid >> 3);
        int arow;
        if (PHASE == 0) arow = (row < rowlim) ? tok[gbase + row] : 0;
        else            arow = r0 + row;
        aptr[j] = asrc + ((size_t)arow << 10) + sw;
        bptr[j] = bsrc + (brow0 + row) * 1024 + sw;
        ldso[j] = ((j << 6) + ((tid >> 3) & ~7)) * 64;   // wave-uniform base; lane adds l*16B
    }

    f32x4 acc[8][4];
#pragma unroll
    for (int mi = 0; mi < 8; ++mi)
#pragma unroll
        for (int ni = 0; ni < 4; ++ni) { acc[mi][ni][0] = 0.f; acc[mi][ni][1] = 0.f; acc[mi][ni][2] = 0.f; acc[mi][ni][3] = 0.f; }

#define STAGE(AS, BS, KO)                                                      \
    {                                                                          \
        _Pragma("unroll")                                                      \
        for (int j = 0; j < 4; ++j) gload_lds16(aptr[j] + (KO), &AS[ldso[j]]); \
        _Pragma("unroll")                                                      \
        for (int j = 0; j < 4; ++j) gload_lds16(bptr[j] + (KO), &BS[ldso[j]]); \
    }

#define COMPUTE(AS, BS)                                                        \
    {                                                                          \
        _Pragma("unroll")                                                      \
        for (int ks = 0; ks < 64; ks += 32) {                                  \
            const int co = (ks + ((l >> 4) << 3)) ^ xk;                        \
            bf16x8 af[8], bfr[4];                                              \
            _Pragma("unroll")                                                  \
            for (int mi = 0; mi < 8; ++mi)                                     \
                af[mi] = *(const bf16x8*)&AS[((wm << 7) + (mi << 4) + l15) * 64 + co]; \
            _Pragma("unroll")                                                  \
            for (int ni = 0; ni < 4; ++ni)                                     \
                bfr[ni] = *(const bf16x8*)&BS[((wn << 6) + (ni << 4) + l15) * 64 + co]; \
            _Pragma("unroll")                                                  \
            for (int mi = 0; mi < 8; ++mi)                                     \
                _Pragma("unroll")                                              \
                for (int ni = 0; ni < 4; ++ni)                                 \
                    acc[mi][ni] = __builtin_amdgcn_mfma_f32_16x16x32_bf16(af[mi], bfr[ni], acc[mi][ni], 0, 0, 0); \
        }                                                                      \
    }

    // prologue: tile 0 into buf0
    STAGE(a0_s, b0_s, 0);
    __syncthreads();

    for (int kc = 0; kc < 16; kc += 2) {
        STAGE(a1_s, b1_s, (kc + 1) << 6);     // next tile, stays in flight
        COMPUTE(a0_s, b0_s);                  // tile kc (covers the flight)
        __syncthreads();                      // staged landed + all reads of buf0 done
        if (kc < 14) STAGE(a0_s, b0_s, (kc + 2) << 6);
        COMPUTE(a1_s, b1_s);                  // tile kc+1
        __syncthreads();
    }
#undef STAGE
#undef COMPUTE

    const int rq = (l >> 4) << 2;
#pragma unroll
    for (int ni = 0; ni < 4; ++ni) {
        int ccol = (wn << 6) + (ni << 4) + l15;
        float bias = (PHASE == 0 ? b1 : b2)[((size_t)e << 10) + nb + ccol];
#pragma unroll
        for (int mi = 0; mi < 8; ++mi) {
            int rbase = (wm << 7) + (mi << 4) + rq;
#pragma unroll
            for (int j = 0; j < 4; ++j) {
                int r = rbase + j;
                if (r < rowlim) {
                    float v = acc[mi][ni][j] + bias;
                    if constexpr (PHASE == 0) {
                        v = fmaxf(v, 0.f);
                        hbuf[(size_t)(r0 + r) * 1024 + nb + ccol] = f2bf(v);
                    } else {
                        int gi = gbase + r;
                        atomicAdd(out + ((size_t)tok[gi] << 10) + nb + ccol, v * coef[gi]);
                    }
                }
            }
        }
    }
}

// ---------------- insurance fallback (ws too small): slow but correct ----------------
__global__ __launch_bounds__(256) void k_naive(const float* __restrict__ x, const float* __restrict__ Wr,
    const float* __restrict__ br, const float* __restrict__ W1, const float* __restrict__ b1,
    const float* __restrict__ W2, const float* __restrict__ b2, float* __restrict__ out)
{
    __shared__ float xs[1024];
    __shared__ float hs[1024];
    __shared__ float red[4];
    __shared__ float lg[8];
    const int tid = threadIdx.x;
    const size_t t = blockIdx.x;
    for (int i = tid; i < 1024; i += 256) xs[i] = x[t * 1024 + i];
    __syncthreads();
    float lacc[8] = {0, 0, 0, 0, 0, 0, 0, 0};
    for (int d = tid; d < 1024; d += 256) {
        float xv = xs[d];
#pragma unroll
        for (int e = 0; e < 8; ++e) lacc[e] += xv * Wr[d * 8 + e];
    }
    for (int e = 0; e < 8; ++e) {
        float v = lacc[e];
        for (int off = 32; off > 0; off >>= 1) v += __shfl_xor(v, off);
        if ((tid & 63) == 0) red[tid >> 6] = v;
        __syncthreads();
        if (tid == 0) lg[e] = red[0] + red[1] + red[2] + red[3] + br[e];
        __syncthreads();
    }
    float v1 = -1e30f, v2 = -1e30f; int i1 = 0, i2 = 0;
    for (int e = 0; e < 8; ++e) {
        float v = lg[e];
        if (v > v1) { v2 = v1; i2 = i1; v1 = v; i1 = e; }
        else if (v > v2) { v2 = v; i2 = e; }
    }
    float c1 = 1.f / (1.f + expf(v2 - v1)), c2 = 1.f - c1;
    float yacc[4] = {0, 0, 0, 0};
    for (int slot = 0; slot < 2; ++slot) {
        int e = slot ? i2 : i1;
        float cw = slot ? c2 : c1;
        __syncthreads();
        float ha[4];
        for (int jb = 0; jb < 4; ++jb) {
            int j = (jb << 8) + tid;
            float a = b1[(e << 10) + j];
            for (int d = 0; d < 1024; ++d) a += xs[d] * W1[(((size_t)e << 10) + d) * 1024 + j];
            ha[jb] = fmaxf(a, 0.f);
        }
        for (int jb = 0; jb < 4; ++jb) hs[(jb << 8) + tid] = ha[jb];
        __syncthreads();
        for (int ob = 0; ob < 4; ++ob) {
            int o = (ob << 8) + tid;
            float a = b2[(e << 10) + o];
            for (int h = 0; h < 1024; ++h) a += hs[h] * W2[(((size_t)e << 10) + h) * 1024 + o];
            yacc[ob] += cw * a;
        }
    }
    for (int ob = 0; ob < 4; ++ob) out[t * 1024 + (ob << 8) + tid] = yacc[ob];
}

extern "C" void kernel_launch(void* const* d_in, const int* in_sizes, int n_in,
                              void* d_out, int out_size, void* d_ws, size_t ws_size,
                              hipStream_t stream) {
    const float* x  = (const float*)d_in[0];
    const float* Wr = (const float*)d_in[1];
    const float* br = (const float*)d_in[2];
    const float* W1 = (const float*)d_in[3];
    const float* b1 = (const float*)d_in[4];
    const float* W2 = (const float*)d_in[5];
    const float* b2 = (const float*)d_in[6];
    float* out = (float*)d_out;

    const size_t OFF_TOK   = (size_t)1 << 20;
    const size_t OFF_COEF  = (size_t)2 << 20;
    const size_t OFF_TINFO = (size_t)3 << 20;
    const size_t OFF_C1    = OFF_TINFO + (size_t)T_TOK * 4;
    const size_t OFF_XBF   = (size_t)4 << 20;
    const size_t OFF_W1T   = OFF_XBF + (size_t)T_TOK * 1024 * 2;          // +32MB
    const size_t OFF_W2T   = OFF_W1T + (size_t)E_NUM * 1024 * 1024 * 2;   // +16MB
    const size_t OFF_H     = OFF_W2T + (size_t)E_NUM * 1024 * 1024 * 2;   // +16MB
    const size_t WS_NEED   = OFF_H + (size_t)(2 * T_TOK + 1024) * 1024 * 2; // h + ragged pad

    if (ws_size < WS_NEED) {
        k_naive<<<T_TOK, 256, 0, stream>>>(x, Wr, br, W1, b1, W2, b2, out);
        return;
    }

    char* ws = (char*)d_ws;
    int*   cnt   = (int*)ws;
    int*   tok   = (int*)(ws + OFF_TOK);
    float* coef  = (float*)(ws + OFF_COEF);
    int*   tinfo = (int*)(ws + OFF_TINFO);
    float* c1arr = (float*)(ws + OFF_C1);
    u16*   xbf   = (u16*)(ws + OFF_XBF);
    u16*   w1t   = (u16*)(ws + OFF_W1T);
    u16*   w2t   = (u16*)(ws + OFF_W2T);
    u16*   hbuf  = (u16*)(ws + OFF_H);

    hipMemsetAsync(cnt, 0, 64, stream);
    hipMemsetAsync(d_out, 0, (size_t)out_size * sizeof(float), stream);
    k_transpose<<<dim3(32, 32, 8), 256, 0, stream>>>(W1, w1t);
    k_transpose<<<dim3(32, 32, 8), 256, 0, stream>>>(W2, w2t);
    k_router<<<4096, 256, 0, stream>>>(x, Wr, br, tinfo, c1arr, xbf);
    k_scatter<<<16, 1024, 0, stream>>>(tinfo, c1arr, cnt, tok, coef);
    dim3 gg(72, 8);
    k_gemm<0><<<gg, 512, 0, stream>>>(cnt, tok, coef, xbf, w1t, w2t, b1, b2, hbuf, out);
    k_gemm<1><<<gg, 512, 0, stream>>>(cnt, tok, coef, xbf, w1t, w2t, b1, b2, hbuf, out);
}